// Round 1
// baseline (14244.341 us; speedup 1.0000x reference)
//
#include <hip/hip_runtime.h>
#include <cmath>

#define T_STEPS 127
#define BATCHN  4096
#define DIN     64
#define HID     256
#define SEQ     128

// ---- workspace float offsets ----
// Wgp: [80][4][256][4]  (gates weights, k-chunked, gate-major, col, 4 k's)
#define WGP_OFF   0
#define BG_OFF    327680      // [1024]  b_ih + b_hh
#define WHP_OFF   328704      // [64][256][4]  heads (mu|var|velo|switch) transposed+packed
#define BH_OFF    394240      // [256]  head biases
#define WNP_OFF   394496      // [16][64][4]  W_next transposed+packed
#define WS_FLOATS 398592

// ---- output float offsets (concat of 5 outputs) ----
#define O_STATES 0L
#define O_GENS   33292288L
#define O_ONOFF  33812480L
#define O_TNG    34332672L
#define O_TG     34856960L

__device__ __forceinline__ float sigmoid_f(float x) {
    return 1.0f / (1.0f + __expf(-x));
}
__device__ __forceinline__ float tanh_f(float x) {
    float cx = fminf(15.0f, fmaxf(-15.0f, x));
    float e = __expf(2.0f * cx);
    return (e - 1.0f) / (e + 1.0f);
}
__device__ __forceinline__ float wave_sum64(float v) {
    #pragma unroll
    for (int off = 32; off > 0; off >>= 1) v += __shfl_xor(v, off, 64);
    return v;
}

__global__ void prep_kernel(const float* __restrict__ W_ih, const float* __restrict__ W_hh,
                            const float* __restrict__ b_ih, const float* __restrict__ b_hh,
                            const float* __restrict__ W_mu, const float* __restrict__ W_var,
                            const float* __restrict__ W_velo, const float* __restrict__ W_switch,
                            const float* __restrict__ b_mu, const float* __restrict__ b_var,
                            const float* __restrict__ b_velo, const float* __restrict__ b_switch,
                            const float* __restrict__ W_next, float* __restrict__ ws) {
    int idx = blockIdx.x * blockDim.x + threadIdx.x;
    int stride = gridDim.x * blockDim.x;
    for (int i = idx; i < WS_FLOATS; i += stride) {
        float v;
        if (i < BG_OFF) {
            int kk = i & 3, j = (i >> 2) & 255, g = (i >> 10) & 3, kc = i >> 12;
            int k = kc * 4 + kk, n = g * 256 + j;
            v = (k < 64) ? W_ih[n * 64 + k] : W_hh[n * 256 + (k - 64)];
        } else if (i < WHP_OFF) {
            int n = i - BG_OFF;
            v = b_ih[n] + b_hh[n];
        } else if (i < BH_OFF) {
            int t = i - WHP_OFF;
            int kk = t & 3, c = (t >> 2) & 255, kc = t >> 10;
            int k = kc * 4 + kk, hsel = c >> 6, jf = c & 63;
            const float* W = (hsel == 0) ? W_mu : (hsel == 1) ? W_var : (hsel == 2) ? W_velo : W_switch;
            v = W[jf * 256 + k];
        } else if (i < WNP_OFF) {
            int c = i - BH_OFF;
            int hsel = c >> 6, jf = c & 63;
            const float* b = (hsel == 0) ? b_mu : (hsel == 1) ? b_var : (hsel == 2) ? b_velo : b_switch;
            v = b[jf];
        } else {
            int t = i - WNP_OFF;
            int kk = t & 3, jf = (t >> 2) & 63, kc = t >> 8;
            int k = kc * 4 + kk;
            v = W_next[jf * 64 + k];
        }
        ws[i] = v;
    }
}

__global__ __launch_bounds__(256, 1)
void model_kernel(const float* __restrict__ data, const float* __restrict__ locs,
                  const float* __restrict__ W_loc, const float* __restrict__ b_loc,
                  const float* __restrict__ b_next, const float* __restrict__ W_gen,
                  const float* __restrict__ b_gen, const float* __restrict__ W_on,
                  const float* __restrict__ b_on, const float* __restrict__ eps,
                  const float* __restrict__ ws, float* __restrict__ out) {
    __shared__ float xh[16][320];          // x in [0,64), h in [64,320)
    __shared__ float cst[16][256];
    __shared__ float headbuf[4][16][64];   // mu, logvar, velo, switch
    __shared__ float zbuf[16][64];

    const int tid = threadIdx.x;
    const int r0 = blockIdx.x * 16;
    const int j = tid;

    // ---- init: x = data[:,0,:], h = locs @ W_loc.T + b_loc, c = 0 ----
    for (int i = tid; i < 16 * 64; i += 256) {
        int r = i >> 6, k = i & 63;
        xh[r][k] = data[(size_t)(r0 + r) * SEQ * DIN + k];
    }
    {
        float w0 = W_loc[j * 2], w1 = W_loc[j * 2 + 1], bl = b_loc[j];
        #pragma unroll
        for (int r = 0; r < 16; ++r) {
            xh[r][64 + j] = locs[(r0 + r) * 2] * w0 + locs[(r0 + r) * 2 + 1] * w1 + bl;
            cst[r][j] = 0.0f;
        }
    }
    if (tid < 16) {
        out[O_TNG + (long)(r0 + tid) * 128] = 0.0f;
        out[O_TG  + (long)(r0 + tid) * 128] = 0.0f;
    }
    __syncthreads();

    const float bgv0 = ws[BG_OFF + j];
    const float bgv1 = ws[BG_OFF + 256 + j];
    const float bgv2 = ws[BG_OFF + 512 + j];
    const float bgv3 = ws[BG_OFF + 768 + j];
    const float bhv  = ws[BH_OFF + j];
    const float bgen = b_gen[0];
    const float bon  = b_on[0];

    const float4* __restrict__ wg = (const float4*)(ws + WGP_OFF);
    const float4* __restrict__ wh = (const float4*)(ws + WHP_OFF);
    const float4* __restrict__ wn = (const float4*)(ws + WNP_OFF);

    for (int t = 0; t < T_STEPS; ++t) {
        // ---------- Phase A: gates = [x|h] @ Wg + bg, LSTM cell ----------
        float ai[16], af[16], ag[16], ao[16];
        #pragma unroll
        for (int r = 0; r < 16; ++r) { ai[r] = bgv0; af[r] = bgv1; ag[r] = bgv2; ao[r] = bgv3; }

        float4 w0 = wg[j], w1 = wg[256 + j], w2 = wg[512 + j], w3 = wg[768 + j];
        #pragma unroll 1
        for (int kc = 0; kc < 80; ++kc) {
            float4 c0 = w0, c1 = w1, c2 = w2, c3 = w3;
            int nb = (kc + 1) * 1024;   // harmless over-read into bg region at kc=79
            w0 = wg[nb + j]; w1 = wg[nb + 256 + j]; w2 = wg[nb + 512 + j]; w3 = wg[nb + 768 + j];
            #pragma unroll
            for (int r = 0; r < 16; ++r) {
                float4 hv = *(const float4*)&xh[r][kc * 4];
                ai[r] += hv.x * c0.x + hv.y * c0.y + hv.z * c0.z + hv.w * c0.w;
                af[r] += hv.x * c1.x + hv.y * c1.y + hv.z * c1.z + hv.w * c1.w;
                ag[r] += hv.x * c2.x + hv.y * c2.y + hv.z * c2.z + hv.w * c2.w;
                ao[r] += hv.x * c3.x + hv.y * c3.y + hv.z * c3.z + hv.w * c3.w;
            }
        }

        float hn[16];
        #pragma unroll
        for (int r = 0; r < 16; ++r) {
            float iv = sigmoid_f(ai[r]);
            float fv = sigmoid_f(af[r]);
            float gv = tanh_f(ag[r]);
            float ov = sigmoid_f(ao[r]);
            float cn = fv * cst[r][j] + iv * gv;
            cst[r][j] = cn;
            hn[r] = ov * tanh_f(cn);
        }
        __syncthreads();               // all gate reads of xh done
        #pragma unroll
        for (int r = 0; r < 16; ++r) xh[r][64 + j] = hn[r];
        __syncthreads();

        // ---------- Phase B: 4 heads = h @ W_head.T + b ----------
        float hacc[16];
        #pragma unroll
        for (int r = 0; r < 16; ++r) hacc[r] = bhv;
        float4 whv = wh[j];
        #pragma unroll 1
        for (int kc = 0; kc < 64; ++kc) {
            float4 cw = whv;
            whv = wh[(kc + 1) * 256 + j];   // harmless over-read at kc=63
            #pragma unroll
            for (int r = 0; r < 16; ++r) {
                float4 hv = *(const float4*)&xh[r][64 + kc * 4];
                hacc[r] += hv.x * cw.x + hv.y * cw.y + hv.z * cw.z + hv.w * cw.w;
            }
        }
        {
            int hsel = j >> 6, feat = j & 63;
            #pragma unroll
            for (int r = 0; r < 16; ++r) headbuf[hsel][r][feat] = hacc[r];
        }
        __syncthreads();

        // ---------- Phase C: z = eps * exp(0.5*logvar) + mu ----------
        {
            int feat = tid & 63, rb = (tid >> 6) * 4;
            #pragma unroll
            for (int rr = 0; rr < 4; ++rr) {
                int r = rb + rr;
                float ep = eps[((size_t)t * BATCHN + r0 + r) * 64 + feat];
                zbuf[r][feat] = ep * __expf(0.5f * headbuf[1][r][feat]) + headbuf[0][r][feat];
            }
        }
        __syncthreads();

        // ---------- Phase D: delta, state update, scalars, totals, outputs ----------
        {
            int feat = tid & 63, rb = (tid >> 6) * 4;
            float dacc[4];
            float bnv = b_next[feat];
            #pragma unroll
            for (int rr = 0; rr < 4; ++rr) dacc[rr] = bnv;
            #pragma unroll 4
            for (int kc = 0; kc < 16; ++kc) {
                float4 cw = wn[kc * 64 + feat];
                #pragma unroll
                for (int rr = 0; rr < 4; ++rr) {
                    float4 zv = *(const float4*)&zbuf[rb + rr][kc * 4];
                    dacc[rr] += zv.x * cw.x + zv.y * cw.y + zv.z * cw.z + zv.w * cw.w;
                }
            }
            float wgv = W_gen[feat];
            float wov = W_on[feat];
            #pragma unroll
            for (int rr = 0; rr < 4; ++rr) {
                int r = rb + rr;
                float sv = (feat == 0) ? 0.0f : fmaxf(xh[r][feat] + dacc[rr], 0.0f);
                float tpre = wave_sum64(sv);
                float gsum = wave_sum64(headbuf[2][r][feat] * wgv);
                float osum = wave_sum64(headbuf[3][r][feat] * wov);
                float gen = fmaxf(gsum + bgen, 0.0f);
                float onf = (osum + bon > 0.0f) ? 1.0f : 0.0f;
                float add = gen * onf;
                if (feat == 0) sv = add;
                float tpost = tpre + add;
                // outputs
                out[O_STATES + (long)(r0 + r) * (127L * 64) + (long)t * 64 + feat] = sv;
                xh[r][feat] = sv;    // x_{t+1}
                if (feat == 0) {
                    long rb127 = (long)(r0 + r) * 127 + t;
                    out[O_GENS  + rb127] = gen;
                    out[O_ONOFF + rb127] = onf;
                    long rb128 = (long)(r0 + r) * 128 + t + 1;
                    out[O_TNG + rb128] = tpre;
                    out[O_TG  + rb128] = tpost;
                }
            }
        }
        __syncthreads();
    }
}

extern "C" void kernel_launch(void* const* d_in, const int* in_sizes, int n_in,
                              void* d_out, int out_size, void* d_ws, size_t ws_size,
                              hipStream_t stream) {
    const float* data     = (const float*)d_in[0];
    const float* locs     = (const float*)d_in[1];
    const float* W_ih     = (const float*)d_in[2];
    const float* W_hh     = (const float*)d_in[3];
    const float* b_ih     = (const float*)d_in[4];
    const float* b_hh     = (const float*)d_in[5];
    const float* W_mu     = (const float*)d_in[6];
    const float* b_mu     = (const float*)d_in[7];
    const float* W_var    = (const float*)d_in[8];
    const float* b_var    = (const float*)d_in[9];
    const float* W_velo   = (const float*)d_in[10];
    const float* b_velo   = (const float*)d_in[11];
    const float* W_switch = (const float*)d_in[12];
    const float* b_switch = (const float*)d_in[13];
    const float* W_gen    = (const float*)d_in[14];
    const float* b_gen    = (const float*)d_in[15];
    const float* W_on     = (const float*)d_in[16];
    const float* b_on     = (const float*)d_in[17];
    const float* W_next   = (const float*)d_in[18];
    const float* b_next   = (const float*)d_in[19];
    const float* W_loc    = (const float*)d_in[20];
    const float* b_loc    = (const float*)d_in[21];
    const float* eps      = (const float*)d_in[22];

    float* ws  = (float*)d_ws;
    float* out = (float*)d_out;

    prep_kernel<<<256, 256, 0, stream>>>(W_ih, W_hh, b_ih, b_hh,
                                         W_mu, W_var, W_velo, W_switch,
                                         b_mu, b_var, b_velo, b_switch,
                                         W_next, ws);
    model_kernel<<<256, 256, 0, stream>>>(data, locs, W_loc, b_loc, b_next,
                                          W_gen, b_gen, W_on, b_on, eps, ws, out);
}

// Round 2
// 7177.997 us; speedup vs baseline: 1.9844x; 1.9844x over previous
//
#include <hip/hip_runtime.h>
#include <cmath>

#define T_STEPS 127
#define BATCHN  4096
#define DIN     64
#define SEQ     128

// ---- workspace layout ----
// bf16 region: GB = gate-weight MFMA fragments, bf16x3 pieces.
//   short index: (((kt*64 + ct)*3 + p)*64 + lane)*8 + j
//   element: piece_p( W[n=ct*16+(lane&15)][k=kt*32+(lane>>4)*8+j] ), W=[W_ih|W_hh] cols
#define GBSH   983040
// float region (float index into ws):
#define F0     491520
#define WHP_F  F0              // heads weights fp32 packed [64][256][4]
#define BG_F   (F0 + 65536)    // gate biases b_ih+b_hh [1024]
#define BH_F   (F0 + 66560)    // head biases [256]
#define WNP_F  (F0 + 66816)    // W_next packed fp32 [16][64][4]
#define F_END  (F0 + 70912)

// ---- output float offsets (concat of 5 outputs) ----
#define O_STATES 0L
#define O_GENS   33292288L
#define O_ONOFF  33812480L
#define O_TNG    34332672L
#define O_TG     34856960L

typedef float  float4v __attribute__((ext_vector_type(4)));
typedef __bf16 bf16x8  __attribute__((ext_vector_type(8)));

__device__ __forceinline__ float sigmoid_f(float x) {
    return 1.0f / (1.0f + __expf(-x));
}
__device__ __forceinline__ float tanh_f(float x) {
    float cx = fminf(15.0f, fmaxf(-15.0f, x));
    float e = __expf(2.0f * cx);
    return (e - 1.0f) / (e + 1.0f);
}
__device__ __forceinline__ float wave_sum64(float v) {
    #pragma unroll
    for (int off = 32; off > 0; off >>= 1) v += __shfl_xor(v, off, 64);
    return v;
}

__global__ void prep_kernel(const float* __restrict__ W_ih, const float* __restrict__ W_hh,
                            const float* __restrict__ b_ih, const float* __restrict__ b_hh,
                            const float* __restrict__ W_mu, const float* __restrict__ W_var,
                            const float* __restrict__ W_velo, const float* __restrict__ W_switch,
                            const float* __restrict__ b_mu, const float* __restrict__ b_var,
                            const float* __restrict__ b_velo, const float* __restrict__ b_switch,
                            const float* __restrict__ W_next, float* __restrict__ ws) {
    int idx = blockIdx.x * blockDim.x + threadIdx.x;
    int stride = gridDim.x * blockDim.x;

    // bf16x3 gate-weight fragments
    __bf16* gb = (__bf16*)ws;
    for (int s = idx; s < GBSH; s += stride) {
        int j = s & 7, l = (s >> 3) & 63, r = s >> 9;
        int p = r % 3, tile = r / 3, ct = tile & 63, kt = tile >> 6;
        int n = ct * 16 + (l & 15);
        int k = kt * 32 + ((l >> 4) << 3) + j;
        float v = (k < 64) ? W_ih[n * 64 + k] : W_hh[n * 256 + (k - 64)];
        __bf16 p0 = (__bf16)v;  float f1 = v - (float)p0;
        __bf16 p1 = (__bf16)f1; float f2 = f1 - (float)p1;
        __bf16 p2 = (__bf16)f2;
        gb[s] = (p == 0) ? p0 : (p == 1) ? p1 : p2;
    }

    // fp32 region
    for (int i = F0 + idx; i < F_END; i += stride) {
        float v;
        if (i < BG_F) {                      // heads packed
            int t = i - WHP_F;
            int kk = t & 3, c = (t >> 2) & 255, kc = t >> 10;
            int k = kc * 4 + kk, hsel = c >> 6, jf = c & 63;
            const float* W = (hsel == 0) ? W_mu : (hsel == 1) ? W_var : (hsel == 2) ? W_velo : W_switch;
            v = W[jf * 256 + k];
        } else if (i < BH_F) {               // gate biases
            int n = i - BG_F;
            v = b_ih[n] + b_hh[n];
        } else if (i < WNP_F) {              // head biases
            int c = i - BH_F;
            int hsel = c >> 6, jf = c & 63;
            const float* b = (hsel == 0) ? b_mu : (hsel == 1) ? b_var : (hsel == 2) ? b_velo : b_switch;
            v = b[jf];
        } else {                             // W_next packed
            int t = i - WNP_F;
            int kk = t & 3, jf = (t >> 2) & 63, kc = t >> 8;
            int k = kc * 4 + kk;
            v = W_next[jf * 64 + k];
        }
        ws[i] = v;
    }
}

__global__ __launch_bounds__(256, 1)
void model_kernel(const float* __restrict__ data, const float* __restrict__ locs,
                  const float* __restrict__ W_loc, const float* __restrict__ b_loc,
                  const float* __restrict__ b_next, const float* __restrict__ W_gen,
                  const float* __restrict__ b_gen, const float* __restrict__ W_on,
                  const float* __restrict__ b_on, const float* __restrict__ eps,
                  const float* __restrict__ ws, float* __restrict__ out) {
    __shared__ float xh[16][340];          // x in [0,64), h in [64,320); stride 340 (16B-aligned, bank-friendly)
    __shared__ float headbuf[4][16][64];   // mu, logvar, velo, switch
    __shared__ float zbuf[16][64];

    const int tid  = threadIdx.x;
    const int r0   = blockIdx.x * 16;
    const int wv   = tid >> 6;      // wave 0..3
    const int ln   = tid & 63;      // lane
    const int ln15 = ln & 15;
    const int quad = ln >> 4;

    // ---- init: x = data[:,0,:], h = locs @ W_loc.T + b_loc ----
    for (int i = tid; i < 16 * 64; i += 256) {
        int r = i >> 6, k = i & 63;
        xh[r][k] = data[(size_t)(r0 + r) * SEQ * DIN + k];
    }
    {
        int j = tid;
        float w0 = W_loc[j * 2], w1 = W_loc[j * 2 + 1], bl = b_loc[j];
        #pragma unroll
        for (int r = 0; r < 16; ++r)
            xh[r][64 + j] = locs[(r0 + r) * 2] * w0 + locs[(r0 + r) * 2 + 1] * w1 + bl;
    }
    if (tid < 16) {
        out[O_TNG + (long)(r0 + tid) * 128] = 0.0f;
        out[O_TG  + (long)(r0 + tid) * 128] = 0.0f;
    }
    __syncthreads();

    // persistent per-lane LSTM cell state, C-fragment layout:
    // c_st[c][rg] = c[row = quad*4+rg][col = wv*64 + c*16 + ln15]
    float c_st[4][4];
    #pragma unroll
    for (int a = 0; a < 4; ++a)
        #pragma unroll
        for (int b = 0; b < 4; ++b) c_st[a][b] = 0.0f;

    float bgc[4][4];
    #pragma unroll
    for (int g = 0; g < 4; ++g)
        #pragma unroll
        for (int c = 0; c < 4; ++c)
            bgc[g][c] = ws[BG_F + g * 256 + wv * 64 + c * 16 + ln15];

    const float bhv  = ws[BH_F + tid];
    const float bgen = b_gen[0];
    const float bon  = b_on[0];

    const bf16x8* __restrict__ gb = (const bf16x8*)ws;
    const float4* __restrict__ wh = (const float4*)(ws + WHP_F);
    const float4* __restrict__ wn = (const float4*)(ws + WNP_F);

    for (int t = 0; t < T_STEPS; ++t) {
        // ---------- Phase A: gates = [x|h] @ Wg^T + bg  (bf16x3, 6-product MFMA) ----------
        float4v acc[4][4];   // [gate][ctl]
        #pragma unroll
        for (int g = 0; g < 4; ++g)
            #pragma unroll
            for (int c = 0; c < 4; ++c) {
                float b = bgc[g][c];
                acc[g][c][0] = b; acc[g][c][1] = b; acc[g][c][2] = b; acc[g][c][3] = b;
            }

        #pragma unroll 1
        for (int kt = 0; kt < 10; ++kt) {
            // A-fragments: lane holds A[m=ln15][k = kt*32 + quad*8 + j], split bf16x3
            const float* arow = &xh[ln15][kt * 32 + quad * 8];
            float4 alo = *(const float4*)arow;
            float4 ahi = *(const float4*)(arow + 4);
            float av[8] = {alo.x, alo.y, alo.z, alo.w, ahi.x, ahi.y, ahi.z, ahi.w};
            bf16x8 A0, A1, A2;
            #pragma unroll
            for (int j = 0; j < 8; ++j) {
                float v = av[j];
                __bf16 p0 = (__bf16)v;  float f1 = v - (float)p0;
                __bf16 p1 = (__bf16)f1; float f2 = f1 - (float)p1;
                __bf16 p2 = (__bf16)f2;
                A0[j] = p0; A1[j] = p1; A2[j] = p2;
            }
            int kbase = kt * 12288 + ln;
            #pragma unroll
            for (int g = 0; g < 4; ++g) {
                #pragma unroll
                for (int c = 0; c < 4; ++c) {
                    int idx = kbase + (g * 16 + wv * 4 + c) * 192;
                    bf16x8 B0 = gb[idx];
                    bf16x8 B1 = gb[idx + 64];
                    bf16x8 B2 = gb[idx + 128];
                    float4v a = acc[g][c];
                    a = __builtin_amdgcn_mfma_f32_16x16x32_bf16(A0, B0, a, 0, 0, 0);
                    a = __builtin_amdgcn_mfma_f32_16x16x32_bf16(A0, B1, a, 0, 0, 0);
                    a = __builtin_amdgcn_mfma_f32_16x16x32_bf16(A1, B0, a, 0, 0, 0);
                    a = __builtin_amdgcn_mfma_f32_16x16x32_bf16(A1, B1, a, 0, 0, 0);
                    a = __builtin_amdgcn_mfma_f32_16x16x32_bf16(A0, B2, a, 0, 0, 0);
                    a = __builtin_amdgcn_mfma_f32_16x16x32_bf16(A2, B0, a, 0, 0, 0);
                    acc[g][c] = a;
                }
            }
        }

        // ---------- LSTM cell elementwise in C-layout; c stays in registers ----------
        float hval[4][4];
        #pragma unroll
        for (int c = 0; c < 4; ++c)
            #pragma unroll
            for (int rg = 0; rg < 4; ++rg) {
                float iv = sigmoid_f(acc[0][c][rg]);
                float fv = sigmoid_f(acc[1][c][rg]);
                float gv = tanh_f(acc[2][c][rg]);
                float ov = sigmoid_f(acc[3][c][rg]);
                float cn = fv * c_st[c][rg] + iv * gv;
                c_st[c][rg] = cn;
                hval[c][rg] = ov * tanh_f(cn);
            }
        __syncthreads();   // all waves finished reading xh for gates
        #pragma unroll
        for (int c = 0; c < 4; ++c)
            #pragma unroll
            for (int rg = 0; rg < 4; ++rg)
                xh[quad * 4 + rg][64 + wv * 64 + c * 16 + ln15] = hval[c][rg];
        __syncthreads();

        // ---------- Phase B: 4 heads = h @ W_head.T + b (fp32 VALU, thread = out col) ----------
        {
            float hacc[16];
            #pragma unroll
            for (int r = 0; r < 16; ++r) hacc[r] = bhv;
            float4 whv = wh[tid];
            #pragma unroll 1
            for (int kc = 0; kc < 64; ++kc) {
                float4 cw = whv;
                whv = wh[(kc + 1) * 256 + tid];   // harmless over-read at kc=63
                #pragma unroll
                for (int r = 0; r < 16; ++r) {
                    float4 hv = *(const float4*)&xh[r][64 + kc * 4];
                    hacc[r] = fmaf(hv.x, cw.x, fmaf(hv.y, cw.y, fmaf(hv.z, cw.z, fmaf(hv.w, cw.w, hacc[r]))));
                }
            }
            int hsel = tid >> 6, feat = tid & 63;
            #pragma unroll
            for (int r = 0; r < 16; ++r) headbuf[hsel][r][feat] = hacc[r];
        }
        __syncthreads();

        // ---------- Phase C: z = eps * exp(0.5*logvar) + mu ----------
        {
            int feat = tid & 63, rb = (tid >> 6) * 4;
            #pragma unroll
            for (int rr = 0; rr < 4; ++rr) {
                int r = rb + rr;
                float ep = eps[((size_t)t * BATCHN + r0 + r) * 64 + feat];
                zbuf[r][feat] = ep * __expf(0.5f * headbuf[1][r][feat]) + headbuf[0][r][feat];
            }
        }
        __syncthreads();

        // ---------- Phase D: delta, state update, scalars, totals, outputs ----------
        {
            int feat = tid & 63, rb = (tid >> 6) * 4;
            float dacc[4];
            float bnv = b_next[feat];
            #pragma unroll
            for (int rr = 0; rr < 4; ++rr) dacc[rr] = bnv;
            #pragma unroll 4
            for (int kc = 0; kc < 16; ++kc) {
                float4 cw = wn[kc * 64 + feat];
                #pragma unroll
                for (int rr = 0; rr < 4; ++rr) {
                    float4 zv = *(const float4*)&zbuf[rb + rr][kc * 4];
                    dacc[rr] = fmaf(zv.x, cw.x, fmaf(zv.y, cw.y, fmaf(zv.z, cw.z, fmaf(zv.w, cw.w, dacc[rr]))));
                }
            }
            float wgv = W_gen[feat];
            float wov = W_on[feat];
            #pragma unroll
            for (int rr = 0; rr < 4; ++rr) {
                int r = rb + rr;
                float sv = (feat == 0) ? 0.0f : fmaxf(xh[r][feat] + dacc[rr], 0.0f);
                float tpre = wave_sum64(sv);
                float gsum = wave_sum64(headbuf[2][r][feat] * wgv);
                float osum = wave_sum64(headbuf[3][r][feat] * wov);
                float gen = fmaxf(gsum + bgen, 0.0f);
                float onf = (osum + bon > 0.0f) ? 1.0f : 0.0f;
                float add = gen * onf;
                if (feat == 0) sv = add;
                float tpost = tpre + add;
                out[O_STATES + (long)(r0 + r) * (127L * 64) + (long)t * 64 + feat] = sv;
                xh[r][feat] = sv;    // x_{t+1}
                if (feat == 0) {
                    long rb127 = (long)(r0 + r) * 127 + t;
                    out[O_GENS  + rb127] = gen;
                    out[O_ONOFF + rb127] = onf;
                    long rb128 = (long)(r0 + r) * 128 + t + 1;
                    out[O_TNG + rb128] = tpre;
                    out[O_TG  + rb128] = tpost;
                }
            }
        }
        __syncthreads();
    }
}

extern "C" void kernel_launch(void* const* d_in, const int* in_sizes, int n_in,
                              void* d_out, int out_size, void* d_ws, size_t ws_size,
                              hipStream_t stream) {
    const float* data     = (const float*)d_in[0];
    const float* locs     = (const float*)d_in[1];
    const float* W_ih     = (const float*)d_in[2];
    const float* W_hh     = (const float*)d_in[3];
    const float* b_ih     = (const float*)d_in[4];
    const float* b_hh     = (const float*)d_in[5];
    const float* W_mu     = (const float*)d_in[6];
    const float* b_mu     = (const float*)d_in[7];
    const float* W_var    = (const float*)d_in[8];
    const float* b_var    = (const float*)d_in[9];
    const float* W_velo   = (const float*)d_in[10];
    const float* b_velo   = (const float*)d_in[11];
    const float* W_switch = (const float*)d_in[12];
    const float* b_switch = (const float*)d_in[13];
    const float* W_gen    = (const float*)d_in[14];
    const float* b_gen    = (const float*)d_in[15];
    const float* W_on     = (const float*)d_in[16];
    const float* b_on     = (const float*)d_in[17];
    const float* W_next   = (const float*)d_in[18];
    const float* b_next   = (const float*)d_in[19];
    const float* W_loc    = (const float*)d_in[20];
    const float* b_loc    = (const float*)d_in[21];
    const float* eps      = (const float*)d_in[22];

    float* ws  = (float*)d_ws;
    float* out = (float*)d_out;

    prep_kernel<<<256, 256, 0, stream>>>(W_ih, W_hh, b_ih, b_hh,
                                         W_mu, W_var, W_velo, W_switch,
                                         b_mu, b_var, b_velo, b_switch,
                                         W_next, ws);
    model_kernel<<<256, 256, 0, stream>>>(data, locs, W_loc, b_loc, b_next,
                                          W_gen, b_gen, W_on, b_on, eps, ws, out);
}